// Round 11
// baseline (419.893 us; speedup 1.0000x reference)
//
#include <hip/hip_runtime.h>
#include <hip/hip_bf16.h>

typedef unsigned short u16;
typedef __bf16 bf16x8 __attribute__((ext_vector_type(8)));
typedef float f32x4 __attribute__((ext_vector_type(4)));
typedef float f32x16 __attribute__((ext_vector_type(16)));
typedef unsigned short u16x8 __attribute__((ext_vector_type(8)));
typedef unsigned short u16x4 __attribute__((ext_vector_type(4)));
typedef unsigned int u32x4 __attribute__((ext_vector_type(4)));

__device__ __forceinline__ u16 f2bf(float f) {
  unsigned u = __builtin_bit_cast(unsigned, f);
  u += 0x7FFFu + ((u >> 16) & 1u);
  return (u16)(u >> 16);
}

// packed f32x2 -> bf16x2 (RNE), single VALU instr
__device__ __forceinline__ unsigned cvt_pk_bf16(float lo, float hi_) {
  unsigned r;
  asm("v_cvt_pk_bf16_f32 %0, %1, %2" : "=v"(r) : "v"(lo), "v"(hi_));
  return r;
}

// async global->LDS, 16B per lane; lds base must be wave-uniform
#define GLD16(gp, lp)                                                          \
  __builtin_amdgcn_global_load_lds(                                            \
      (const __attribute__((address_space(1))) void*)(gp),                     \
      (__attribute__((address_space(3))) void*)(lp), 16, 0, 0)

// ---------------- cast kernels ----------------

__global__ __launch_bounds__(256) void cast_f32_bf16(
    const float* __restrict__ in, u16* __restrict__ out, int n4) {
  int i = blockIdx.x * 256 + threadIdx.x;
  if (i >= n4) return;
  float4 v = ((const float4*)in)[i];
  u16x4 o = {f2bf(v.x), f2bf(v.y), f2bf(v.z), f2bf(v.w)};
  *(u16x4*)(out + (size_t)i * 4) = o;
}

// out[c][r] = (bf16) in[r][c];  in: R x C f32, out: C x R bf16
__global__ __launch_bounds__(256) void transpose_cast(
    const float* __restrict__ in, u16* __restrict__ out, int R, int C) {
  __shared__ float t[32][33];
  int c0 = blockIdx.x * 32, r0 = blockIdx.y * 32;
  int tx = threadIdx.x, ty = threadIdx.y;
#pragma unroll
  for (int k = 0; k < 4; ++k)
    t[ty + 8 * k][tx] = in[(size_t)(r0 + ty + 8 * k) * C + c0 + tx];
  __syncthreads();
#pragma unroll
  for (int k = 0; k < 4; ++k)
    out[(size_t)(c0 + ty + 8 * k) * R + r0 + tx] = f2bf(t[tx][ty + 8 * k]);
}

// ---------------- GEMM: C[M,N] = A[M,K] * Bt[N,K]^T  (bf16, 128x128x64) ----------------
// BK=64: halves barrier drains per MFMA vs BK=32. 8-chunk XOR pre-swizzle both sides.

template <int EPI>
__global__ __launch_bounds__(256) void gemm_bt(
    const u16* __restrict__ A, const u16* __restrict__ Bt, int K,
    u16* __restrict__ Qd, u16* __restrict__ Kd, u16* __restrict__ Vd,
    float* __restrict__ Od, int N) {
  __shared__ u16 As[128 * 64];
  __shared__ u16 Bs[128 * 64];
  int tid = threadIdx.x;
  int l = tid & 63, w = tid >> 6;
  int wr = w >> 1, wc = w & 1;
  int lr = l & 15, lg = l >> 4;
  int m0 = blockIdx.y * 128, n0 = blockIdx.x * 128;

  f32x4 acc[4][4];
  f32x4 z4 = {0.f, 0.f, 0.f, 0.f};
#pragma unroll
  for (int mi = 0; mi < 4; ++mi)
#pragma unroll
    for (int ni = 0; ni < 4; ++ni) acc[mi][ni] = z4;

  for (int kt = 0; kt < K; kt += 64) {
#pragma unroll
    for (int it = 0; it < 4; ++it) {
      int q = it * 256 + tid;        // 1024 16B-chunks: 128 rows x 8 chunks
      int r = q >> 3, s = q & 7;
      int sw = (s ^ (r & 7)) << 3;   // source pre-swizzle; LDS dest linear
      GLD16(A + (size_t)(m0 + r) * K + kt + sw, As + it * 2048 + w * 512);
      GLD16(Bt + (size_t)(n0 + r) * K + kt + sw, Bs + it * 2048 + w * 512);
    }
    __syncthreads();

#pragma unroll
    for (int ks2 = 0; ks2 < 2; ++ks2) {
      bf16x8 af[4], bfv[4];
#pragma unroll
      for (int mi = 0; mi < 4; ++mi) {
        int row = wr * 64 + mi * 16 + lr;
        af[mi] = *(const bf16x8*)&As[row * 64 + (((ks2 * 4 + lg) ^ (row & 7)) << 3)];
      }
#pragma unroll
      for (int ni = 0; ni < 4; ++ni) {
        int col = wc * 64 + ni * 16 + lr;
        bfv[ni] = *(const bf16x8*)&Bs[col * 64 + (((ks2 * 4 + lg) ^ (col & 7)) << 3)];
      }
#pragma unroll
      for (int mi = 0; mi < 4; ++mi)
#pragma unroll
        for (int ni = 0; ni < 4; ++ni)
          acc[mi][ni] = __builtin_amdgcn_mfma_f32_16x16x32_bf16(
              af[mi], bfv[ni], acc[mi][ni], 0, 0, 0);
    }
    __syncthreads();
  }

  if (EPI == 0) {
    int s_blk = n0 >> 10;  // 0=Q 1=K 2=V (tile never straddles)
    u16* dst = (s_blk == 0) ? Qd : ((s_blk == 1) ? Kd : Vd);
#pragma unroll
    for (int mi = 0; mi < 4; ++mi)
#pragma unroll
      for (int ni = 0; ni < 4; ++ni)
#pragma unroll
        for (int i = 0; i < 4; ++i) {
          int m = m0 + wr * 64 + mi * 16 + lg * 4 + i;
          int n = n0 + wc * 64 + ni * 16 + lr;
          int b = m >> 11, t = m & 2047;
          int c = n & 1023, h = c >> 6, d = c & 63;
          dst[((size_t)(b * 16 + h) * 2048 + t) * 64 + d] = f2bf(acc[mi][ni][i]);
        }
  } else {
#pragma unroll
    for (int mi = 0; mi < 4; ++mi)
#pragma unroll
      for (int ni = 0; ni < 4; ++ni)
#pragma unroll
        for (int i = 0; i < 4; ++i) {
          int m = m0 + wr * 64 + mi * 16 + lg * 4 + i;
          int n = n0 + wc * 64 + ni * 16 + lr;
          Od[(size_t)m * N + n] = acc[mi][ni][i];
        }
  }
}

// ---------------- flash attention (causal), swapped-QK^T, 32x32x16 MFMA ----------------
// Q,K,V: bf16 [64 bh][2048][64] ; Y: bf16 [8192][1024] at (b*2048+q)*1024 + h*64 + d
// Block: 2 waves x 32 q-rows = 64-row q-tile. Grid: 32 qt x 64 bh = 2048 blocks,
// heavy-first (LPT). T14 reg-staged K+V (no global_load_lds): single-buffer
// Ks+Vt = 16 KB LDS -> ~8 blocks/CU residency (2x R10). Loads for tile j+1
// issued right after barrier [A], landing under tile j's compute.

__global__ __launch_bounds__(128, 4) void attn_fwd(
    const u16* __restrict__ Qg, const u16* __restrict__ Kg,
    const u16* __restrict__ Vg, u16* __restrict__ Yg) {
  __shared__ u16 Ks[64 * 64];  // [k][chunk c] = global chunk c^(k&7)
  __shared__ u16 Vt[64 * 64];  // V^T [d][t], t-octet swizzled by (t>>3)^(d&7)^(d>>3)

  int tid = threadIdx.x;
  int l = tid & 63, w = tid >> 6;  // 2 waves
  int l31 = l & 31, hi = l >> 5, l7 = l & 7;
  int bid = blockIdx.x;
  int qt = 31 - (bid >> 6);  // heavy tiles dispatched first (LPT)
  int bh = bid & 63;
  const u16* Qb = Qg + (size_t)bh * 131072;
  const u16* Kb = Kg + (size_t)bh * 131072;
  const u16* Vb = Vg + (size_t)bh * 131072;
  int b = bh >> 4, h = bh & 15;

  int t8 = tid >> 3, dq = tid & 7;  // staging coords
  int q0w = qt * 64 + w * 32;
  int jn = qt;

  // Q fragments in registers (B-operand: col=q=l31, rows d=16*ds+8*hi+j)
  bf16x8 qreg[4];
#pragma unroll
  for (int ds = 0; ds < 4; ++ds)
    qreg[ds] =
        *(const bf16x8*)(Qb + (size_t)(q0w + l31) * 64 + ds * 16 + hi * 8);

  f32x16 o_acc[2];
#pragma unroll
  for (int dt = 0; dt < 2; ++dt)
#pragma unroll
    for (int r = 0; r < 16; ++r) o_acc[dt][r] = 0.f;
  float m_run = -3e38f, l_run = 0.f;

  // prologue: load K(0), V(0) into regs
  u16x8 kreg[4], va[2], vb[2];
#pragma unroll
  for (int it = 0; it < 4; ++it) {
    int q = it * 128 + tid;
    int r = q >> 3, s = q & 7;
    kreg[it] = *(const u16x8*)(Kb + (size_t)r * 64 + s * 8);
  }
#pragma unroll
  for (int it = 0; it < 2; ++it) {
    int rr = it * 16 + t8;  // rows 2rr, 2rr+1
    va[it] = *(const u16x8*)(Vb + (size_t)(2 * rr) * 64 + dq * 8);
    vb[it] = *(const u16x8*)(Vb + (size_t)(2 * rr + 1) * 64 + dq * 8);
  }

  for (int j = 0; j <= jn; ++j) {
    int kv0 = j * 64;
    // write K tile j: LDS[r][c] = G[r][c^(r&7)] (4x ds_write_b128, conflict-free)
#pragma unroll
    for (int it = 0; it < 4; ++it) {
      int q = it * 128 + tid;
      int r = q >> 3, s = q & 7;
      *(u16x8*)(Ks + r * 64 + ((s ^ (r & 7)) << 3)) = kreg[it];
    }
    // write V^T tile j: paired u32 (t=2rr,2rr+1), swizzled, ~2-way banks
#pragma unroll
    for (int it = 0; it < 2; ++it) {
      int rr = it * 16 + t8;
#pragma unroll
      for (int jj = 0; jj < 8; ++jj) {
        int d = dq * 8 + jj;
        unsigned wv = (unsigned)va[it][jj] | ((unsigned)vb[it][jj] << 16);
        *(unsigned*)(Vt + d * 64 + (((rr >> 2) ^ jj ^ dq) << 3) +
                     ((rr & 3) << 1)) = wv;
      }
    }
    __syncthreads();  // [A] Ks/Vt tile j visible

    if (j < jn) {  // issue next-tile loads now; land under compute below
      int kv1 = kv0 + 64;
#pragma unroll
      for (int it = 0; it < 4; ++it) {
        int q = it * 128 + tid;
        int r = q >> 3, s = q & 7;
        kreg[it] = *(const u16x8*)(Kb + (size_t)(kv1 + r) * 64 + s * 8);
      }
#pragma unroll
      for (int it = 0; it < 2; ++it) {
        int rr = it * 16 + t8;
        va[it] = *(const u16x8*)(Vb + (size_t)(kv1 + 2 * rr) * 64 + dq * 8);
        vb[it] = *(const u16x8*)(Vb + (size_t)(kv1 + 2 * rr + 1) * 64 + dq * 8);
      }
    }

    {
      int qg = q0w + l31;
      bf16x8 kf[2][4];
#pragma unroll
      for (int kt = 0; kt < 2; ++kt)
#pragma unroll
        for (int ds = 0; ds < 4; ++ds)
          kf[kt][ds] = *(const bf16x8*)&Ks[(32 * kt + l31) * 64 +
                                           (((2 * ds + hi) ^ l7) << 3)];
      // QK^T swapped: S^T[k][q]; lane col=q=l31, rows k=crow(r,hi)
      f32x16 sa[2];
      __builtin_amdgcn_s_setprio(1);
#pragma unroll
      for (int kt = 0; kt < 2; ++kt) {
        f32x16 acc;
#pragma unroll
        for (int r = 0; r < 16; ++r) acc[r] = 0.f;
#pragma unroll
        for (int ds = 0; ds < 4; ++ds)
          acc = __builtin_amdgcn_mfma_f32_32x32x16_bf16(kf[kt][ds], qreg[ds],
                                                        acc, 0, 0, 0);
        sa[kt] = acc;
      }
      __builtin_amdgcn_s_setprio(0);

      float mloc = -3e38f;
      if (kv0 + 63 > q0w) {  // masking tile
#pragma unroll
        for (int kt = 0; kt < 2; ++kt)
#pragma unroll
          for (int r = 0; r < 16; ++r) {
            int kg = kv0 + kt * 32 + ((r & 3) + 8 * (r >> 2) + 4 * hi);
            float v = sa[kt][r];
            v = (kg <= qg) ? v : -8e30f;
            sa[kt][r] = v;
            mloc = fmaxf(mloc, v);
          }
      } else {
#pragma unroll
        for (int kt = 0; kt < 2; ++kt)
#pragma unroll
          for (int r = 0; r < 16; ++r) mloc = fmaxf(mloc, sa[kt][r]);
      }
      float mx = fmaxf(mloc, __shfl_xor(mloc, 32)) * 0.125f;
      if (!__all(mx <= m_run + 8.f)) {  // defer-max (T13)
        float mn = fmaxf(m_run, mx);
        float fsc = __expf(m_run - mn);
        m_run = mn;
        l_run *= fsc;
#pragma unroll
        for (int r = 0; r < 16; ++r) {
          float fv = __shfl(fsc, (r & 3) + 8 * (r >> 2) + 4 * hi + 32 * hi);
          o_acc[0][r] *= fv;
          o_acc[1][r] *= fv;
        }
      }
      // p = exp2(s*0.125*log2e - m*log2e): 1 fma + 1 exp2 per element
      float mm = m_run * 1.44269504f;
      float lloc = 0.f;
#pragma unroll
      for (int kt = 0; kt < 2; ++kt)
#pragma unroll
        for (int r = 0; r < 16; ++r) {
          float p = exp2f(__builtin_fmaf(sa[kt][r], 0.18033688f, -mm));
          sa[kt][r] = p;
          lloc += p;
        }
      l_run += lloc + __shfl_xor(lloc, 32);
      // pack P to bf16 pairs (1 cvt_pk each)
      unsigned pk0[8], pk1[8];
#pragma unroll
      for (int m = 0; m < 8; ++m) {
        pk0[m] = cvt_pk_bf16(sa[0][2 * m], sa[0][2 * m + 1]);
        pk1[m] = cvt_pk_bf16(sa[1][2 * m], sa[1][2 * m + 1]);
      }
      // V^T fragments (loaded late to bound live VGPRs)
      bf16x8 vf[2][4];
#pragma unroll
      for (int dt = 0; dt < 2; ++dt)
#pragma unroll
        for (int ks = 0; ks < 4; ++ks) {
          int d = 32 * dt + l31;
          int ch = ((2 * ks + hi) ^ (d & 7) ^ ((d >> 3) & 7)) & 7;
          vf[dt][ks] = *(const bf16x8*)&Vt[d * 64 + (ch << 3)];
        }
      // build PV A-frags via one shfl_xor(32) pair per kstep
#pragma unroll
      for (int ks = 0; ks < 4; ++ks) {
        int c0 = 4 * (ks & 1);
        unsigned a0 = (ks < 2) ? pk0[c0] : pk1[c0];
        unsigned a1 = (ks < 2) ? pk0[c0 + 1] : pk1[c0 + 1];
        unsigned a2 = (ks < 2) ? pk0[c0 + 2] : pk1[c0 + 2];
        unsigned a3 = (ks < 2) ? pk0[c0 + 3] : pk1[c0 + 3];
        unsigned pubX = hi ? a0 : a2;
        unsigned pubY = hi ? a1 : a3;
        unsigned rx = (unsigned)__shfl_xor((int)pubX, 32);
        unsigned ry = (unsigned)__shfl_xor((int)pubY, 32);
        u32x4 fa;
        fa.x = hi ? rx : a0;
        fa.y = hi ? ry : a1;
        fa.z = hi ? a2 : rx;
        fa.w = hi ? a3 : ry;
        bf16x8 paf = __builtin_bit_cast(bf16x8, fa);
        __builtin_amdgcn_s_setprio(1);
#pragma unroll
        for (int dt = 0; dt < 2; ++dt)
          o_acc[dt] = __builtin_amdgcn_mfma_f32_32x32x16_bf16(
              paf, vf[dt][ks], o_acc[dt], 0, 0, 0);
        __builtin_amdgcn_s_setprio(0);
      }
    }
    __syncthreads();  // [B] Ks/Vt reads done before next tile's writes
  }

  // epilogue: normalize and store
#pragma unroll
  for (int r = 0; r < 16; ++r) {
    int crow = (r & 3) + 8 * (r >> 2) + 4 * hi;
    float li = __shfl(l_run, crow + 32 * hi);
    float inv = 1.f / li;
    int q = q0w + crow;
#pragma unroll
    for (int dt = 0; dt < 2; ++dt) {
      float y = o_acc[dt][r] * inv;
      Yg[(size_t)(b * 2048 + q) * 1024 + h * 64 + dt * 32 + l31] = f2bf(y);
    }
  }
}

// ---------------- launch ----------------

extern "C" void kernel_launch(void* const* d_in, const int* in_sizes, int n_in,
                              void* d_out, int out_size, void* d_ws, size_t ws_size,
                              hipStream_t stream) {
  const float* x = (const float*)d_in[0];
  const float* w_qkv = (const float*)d_in[1];
  const float* w_proj = (const float*)d_in[2];
  float* out = (float*)d_out;
  u16* ws = (u16*)d_ws;

  u16* xb = ws;                  // 8388608 elems (B*T*C)
  u16* wq = xb + 8388608;        // 3145728 (3C x C, transposed)
  u16* wp = wq + 3145728;        // 1048576 (C x C, transposed)
  u16* Qb = wp + 1048576;        // 8388608 each, [B,H,T,D]
  u16* Kb = Qb + 8388608;
  u16* Vb = Kb + 8388608;
  u16* Yb = xb;                  // alias: x_bf16 dead after QKV GEMM

  cast_f32_bf16<<<8192, 256, 0, stream>>>(x, xb, 2097152);
  transpose_cast<<<dim3(96, 32), dim3(32, 8), 0, stream>>>(w_qkv, wq, 1024, 3072);
  transpose_cast<<<dim3(32, 32), dim3(32, 8), 0, stream>>>(w_proj, wp, 1024, 1024);
  gemm_bt<0><<<dim3(24, 64), 256, 0, stream>>>(xb, wq, 1024, Qb, Kb, Vb, nullptr, 3072);
  attn_fwd<<<2048, 128, 0, stream>>>(Qb, Kb, Vb, Yb);
  gemm_bt<1><<<dim3(8, 64), 256, 0, stream>>>(Yb, wp, 1024, nullptr, nullptr, nullptr, out, 1024);
}

// Round 12
// 173.924 us; speedup vs baseline: 2.4142x; 2.4142x over previous
//
#include <hip/hip_runtime.h>
#include <hip/hip_bf16.h>

typedef unsigned short u16;
typedef __bf16 bf16x8 __attribute__((ext_vector_type(8)));
typedef float f32x4 __attribute__((ext_vector_type(4)));
typedef float f32x16 __attribute__((ext_vector_type(16)));
typedef unsigned short u16x8 __attribute__((ext_vector_type(8)));
typedef unsigned short u16x4 __attribute__((ext_vector_type(4)));
typedef unsigned int u32x4 __attribute__((ext_vector_type(4)));

__device__ __forceinline__ u16 f2bf(float f) {
  unsigned u = __builtin_bit_cast(unsigned, f);
  u += 0x7FFFu + ((u >> 16) & 1u);
  return (u16)(u >> 16);
}

// packed f32x2 -> bf16x2 (RNE), single VALU instr
__device__ __forceinline__ unsigned cvt_pk_bf16(float lo, float hi_) {
  unsigned r;
  asm("v_cvt_pk_bf16_f32 %0, %1, %2" : "=v"(r) : "v"(lo), "v"(hi_));
  return r;
}

// async global->LDS, 16B per lane; lds base must be wave-uniform
#define GLD16(gp, lp)                                                          \
  __builtin_amdgcn_global_load_lds(                                            \
      (const __attribute__((address_space(1))) void*)(gp),                     \
      (__attribute__((address_space(3))) void*)(lp), 16, 0, 0)

// ---------------- cast kernels ----------------

__global__ __launch_bounds__(256) void cast_f32_bf16(
    const float* __restrict__ in, u16* __restrict__ out, int n4) {
  int i = blockIdx.x * 256 + threadIdx.x;
  if (i >= n4) return;
  float4 v = ((const float4*)in)[i];
  u16x4 o = {f2bf(v.x), f2bf(v.y), f2bf(v.z), f2bf(v.w)};
  *(u16x4*)(out + (size_t)i * 4) = o;
}

// out[c][r] = (bf16) in[r][c];  in: R x C f32, out: C x R bf16
__global__ __launch_bounds__(256) void transpose_cast(
    const float* __restrict__ in, u16* __restrict__ out, int R, int C) {
  __shared__ float t[32][33];
  int c0 = blockIdx.x * 32, r0 = blockIdx.y * 32;
  int tx = threadIdx.x, ty = threadIdx.y;
#pragma unroll
  for (int k = 0; k < 4; ++k)
    t[ty + 8 * k][tx] = in[(size_t)(r0 + ty + 8 * k) * C + c0 + tx];
  __syncthreads();
#pragma unroll
  for (int k = 0; k < 4; ++k)
    out[(size_t)(c0 + ty + 8 * k) * R + r0 + tx] = f2bf(t[tx][ty + 8 * k]);
}

// ---------------- GEMM: C[M,N] = A[M,K] * Bt[N,K]^T  (bf16, 128x128x64) ----------------
// BK=64: halves barrier drains per MFMA vs BK=32. 8-chunk XOR pre-swizzle both sides.

template <int EPI>
__global__ __launch_bounds__(256) void gemm_bt(
    const u16* __restrict__ A, const u16* __restrict__ Bt, int K,
    u16* __restrict__ Qd, u16* __restrict__ Kd, u16* __restrict__ Vd,
    float* __restrict__ Od, int N) {
  __shared__ u16 As[128 * 64];
  __shared__ u16 Bs[128 * 64];
  int tid = threadIdx.x;
  int l = tid & 63, w = tid >> 6;
  int wr = w >> 1, wc = w & 1;
  int lr = l & 15, lg = l >> 4;
  int m0 = blockIdx.y * 128, n0 = blockIdx.x * 128;

  f32x4 acc[4][4];
  f32x4 z4 = {0.f, 0.f, 0.f, 0.f};
#pragma unroll
  for (int mi = 0; mi < 4; ++mi)
#pragma unroll
    for (int ni = 0; ni < 4; ++ni) acc[mi][ni] = z4;

  for (int kt = 0; kt < K; kt += 64) {
#pragma unroll
    for (int it = 0; it < 4; ++it) {
      int q = it * 256 + tid;        // 1024 16B-chunks: 128 rows x 8 chunks
      int r = q >> 3, s = q & 7;
      int sw = (s ^ (r & 7)) << 3;   // source pre-swizzle; LDS dest linear
      GLD16(A + (size_t)(m0 + r) * K + kt + sw, As + it * 2048 + w * 512);
      GLD16(Bt + (size_t)(n0 + r) * K + kt + sw, Bs + it * 2048 + w * 512);
    }
    __syncthreads();

#pragma unroll
    for (int ks2 = 0; ks2 < 2; ++ks2) {
      bf16x8 af[4], bfv[4];
#pragma unroll
      for (int mi = 0; mi < 4; ++mi) {
        int row = wr * 64 + mi * 16 + lr;
        af[mi] = *(const bf16x8*)&As[row * 64 + (((ks2 * 4 + lg) ^ (row & 7)) << 3)];
      }
#pragma unroll
      for (int ni = 0; ni < 4; ++ni) {
        int col = wc * 64 + ni * 16 + lr;
        bfv[ni] = *(const bf16x8*)&Bs[col * 64 + (((ks2 * 4 + lg) ^ (col & 7)) << 3)];
      }
#pragma unroll
      for (int mi = 0; mi < 4; ++mi)
#pragma unroll
        for (int ni = 0; ni < 4; ++ni)
          acc[mi][ni] = __builtin_amdgcn_mfma_f32_16x16x32_bf16(
              af[mi], bfv[ni], acc[mi][ni], 0, 0, 0);
    }
    __syncthreads();
  }

  if (EPI == 0) {
    int s_blk = n0 >> 10;  // 0=Q 1=K 2=V (tile never straddles)
    u16* dst = (s_blk == 0) ? Qd : ((s_blk == 1) ? Kd : Vd);
#pragma unroll
    for (int mi = 0; mi < 4; ++mi)
#pragma unroll
      for (int ni = 0; ni < 4; ++ni)
#pragma unroll
        for (int i = 0; i < 4; ++i) {
          int m = m0 + wr * 64 + mi * 16 + lg * 4 + i;
          int n = n0 + wc * 64 + ni * 16 + lr;
          int b = m >> 11, t = m & 2047;
          int c = n & 1023, h = c >> 6, d = c & 63;
          dst[((size_t)(b * 16 + h) * 2048 + t) * 64 + d] = f2bf(acc[mi][ni][i]);
        }
  } else {
#pragma unroll
    for (int mi = 0; mi < 4; ++mi)
#pragma unroll
      for (int ni = 0; ni < 4; ++ni)
#pragma unroll
        for (int i = 0; i < 4; ++i) {
          int m = m0 + wr * 64 + mi * 16 + lg * 4 + i;
          int n = n0 + wc * 64 + ni * 16 + lr;
          Od[(size_t)m * N + n] = acc[mi][ni][i];
        }
  }
}

// ---------------- flash attention (causal), swapped-QK^T, 32x32x16 MFMA ----------------
// Q,K,V: bf16 [64 bh][2048][64] ; Y: bf16 [8192][1024] at (b*2048+q)*1024 + h*64 + d
// Block: 2 waves x 32 q-rows = 64-row q-tile. Grid: 32 qt x 64 bh = 2048 blocks,
// heavy-first (LPT). K via global_load_lds double-buffer; V^T staged with
// k-PERMUTED t-positions (pi = swap bits1,2 of t>>1) so the QK output's native
// per-lane k-order feeds PV's A-operand directly -- zero pack shuffles.

__global__ __launch_bounds__(128, 3) void attn_fwd(
    const u16* __restrict__ Qg, const u16* __restrict__ Kg,
    const u16* __restrict__ Vg, u16* __restrict__ Yg) {
  __shared__ u16 Ks[2][64 * 64];  // [k][d], octet c holds global octet c^(k&7)
  __shared__ u16 Vt[64 * 64];     // V^T [d][pi(t)], octet swizzle (p>>3)^(d&7)^(d>>3)

  int tid = threadIdx.x;
  int l = tid & 63, w = tid >> 6;  // 2 waves
  int l31 = l & 31, hi = l >> 5, l7 = l & 7;
  int bid = blockIdx.x;
  int qt = 31 - (bid >> 6);  // heavy tiles dispatched first (LPT)
  int bh = bid & 63;
  const u16* Qb = Qg + (size_t)bh * 131072;
  const u16* Kb = Kg + (size_t)bh * 131072;
  const u16* Vb = Vg + (size_t)bh * 131072;
  int b = bh >> 4, h = bh & 15;

  int t8 = tid >> 3, dq = tid & 7;  // staging coords
  int q0w = qt * 64 + w * 32;
  int jn = qt;

  // Q fragments in registers (B-operand: col=q=l31, rows d=16*ds+8*hi+j)
  bf16x8 qreg[4];
#pragma unroll
  for (int ds = 0; ds < 4; ++ds)
    qreg[ds] =
        *(const bf16x8*)(Qb + (size_t)(q0w + l31) * 64 + ds * 16 + hi * 8);

  f32x16 o_acc[2];
#pragma unroll
  for (int dt = 0; dt < 2; ++dt)
#pragma unroll
    for (int r = 0; r < 16; ++r) o_acc[dt][r] = 0.f;
  float m_run = -3e38f, l_run = 0.f;  // l_run: per-half partial (summed at end)

  // prologue: stage K(0) async, V(0) row-pairs into regs
  u16x8 va[2], vb[2];
#pragma unroll
  for (int it = 0; it < 4; ++it) {
    int r = it * 16 + t8;
    GLD16(Kb + (size_t)r * 64 + ((dq ^ (r & 7)) << 3),
          &Ks[0][it * 1024 + w * 512]);
  }
#pragma unroll
  for (int it = 0; it < 2; ++it) {
    int rr = it * 16 + t8;  // rows 2rr, 2rr+1
    va[it] = *(const u16x8*)(Vb + (size_t)(2 * rr) * 64 + dq * 8);
    vb[it] = *(const u16x8*)(Vb + (size_t)(2 * rr + 1) * 64 + dq * 8);
  }

  for (int j = 0; j <= jn; ++j) {
    int kv0 = j * 64;
    const u16* ksb = Ks[j & 1];
    // write V^T tile j at pi-permuted t-positions: rr2 = rr with bits1,2 swapped
#pragma unroll
    for (int it = 0; it < 2; ++it) {
      int rr = it * 16 + t8;
      int rr2 = (rr & ~6) | ((rr & 2) << 1) | ((rr & 4) >> 1);
#pragma unroll
      for (int jj = 0; jj < 8; ++jj) {
        int d = dq * 8 + jj;
        unsigned wv = (unsigned)va[it][jj] | ((unsigned)vb[it][jj] << 16);
        *(unsigned*)(Vt + d * 64 + (((rr2 >> 2) ^ jj ^ dq) << 3) +
                     ((rr2 & 3) << 1)) = wv;
      }
    }
    __syncthreads();  // [A] K(j) landed (vmcnt drain), Vt visible

    if (j < jn) {  // prefetch next tile: hides HBM latency under compute
      int kv1 = kv0 + 64;
#pragma unroll
      for (int it = 0; it < 4; ++it) {
        int r = it * 16 + t8;
        GLD16(Kb + (size_t)(kv1 + r) * 64 + ((dq ^ (r & 7)) << 3),
              &Ks[(j + 1) & 1][it * 1024 + w * 512]);
      }
#pragma unroll
      for (int it = 0; it < 2; ++it) {
        int rr = it * 16 + t8;
        va[it] = *(const u16x8*)(Vb + (size_t)(kv1 + 2 * rr) * 64 + dq * 8);
        vb[it] = *(const u16x8*)(Vb + (size_t)(kv1 + 2 * rr + 1) * 64 + dq * 8);
      }
    }

    {
      int qg = q0w + l31;
      bf16x8 kf[2][4];
#pragma unroll
      for (int kt = 0; kt < 2; ++kt)
#pragma unroll
        for (int ds = 0; ds < 4; ++ds)
          kf[kt][ds] = *(const bf16x8*)&ksb[(32 * kt + l31) * 64 +
                                            (((2 * ds + hi) ^ l7) << 3)];
      // QK^T swapped: S^T[k][q]; lane col=q=l31, rows k=crow(r,hi)
      f32x16 sa[2];
      __builtin_amdgcn_s_setprio(1);
#pragma unroll
      for (int kt = 0; kt < 2; ++kt) {
        f32x16 acc;
#pragma unroll
        for (int r = 0; r < 16; ++r) acc[r] = 0.f;
#pragma unroll
        for (int ds = 0; ds < 4; ++ds)
          acc = __builtin_amdgcn_mfma_f32_32x32x16_bf16(kf[kt][ds], qreg[ds],
                                                        acc, 0, 0, 0);
        sa[kt] = acc;
      }
      __builtin_amdgcn_s_setprio(0);

      float mloc = -3e38f;
      if (kv0 + 63 > q0w) {  // masking tile
#pragma unroll
        for (int kt = 0; kt < 2; ++kt)
#pragma unroll
          for (int r = 0; r < 16; ++r) {
            int kg = kv0 + kt * 32 + ((r & 3) + 8 * (r >> 2) + 4 * hi);
            float v = sa[kt][r];
            v = (kg <= qg) ? v : -8e30f;
            sa[kt][r] = v;
            mloc = fmaxf(mloc, v);
          }
      } else {
#pragma unroll
        for (int kt = 0; kt < 2; ++kt)
#pragma unroll
          for (int r = 0; r < 16; ++r) mloc = fmaxf(mloc, sa[kt][r]);
      }
      float mx = fmaxf(mloc, __shfl_xor(mloc, 32)) * 0.125f;
      if (!__all(mx <= m_run + 8.f)) {  // defer-max (T13)
        float mn = fmaxf(m_run, mx);
        float fsc = __expf(m_run - mn);
        m_run = mn;
        l_run *= fsc;  // row-uniform fsc: per-half partial stays consistent
#pragma unroll
        for (int r = 0; r < 16; ++r) {
          float fv = __shfl(fsc, (r & 3) + 8 * (r >> 2) + 4 * hi + 32 * hi);
          o_acc[0][r] *= fv;
          o_acc[1][r] *= fv;
        }
      }
      // p = exp2(s*0.125*log2e - m*log2e): 1 fma + 1 exp2 per element
      float mm = m_run * 1.44269504f;
      float lloc = 0.f;
#pragma unroll
      for (int kt = 0; kt < 2; ++kt)
#pragma unroll
        for (int r = 0; r < 16; ++r) {
          float p = exp2f(__builtin_fmaf(sa[kt][r], 0.18033688f, -mm));
          sa[kt][r] = p;
          lloc += p;
        }
      l_run += lloc;  // cross-half sum deferred to epilogue
      // pack P to bf16 pairs (1 cvt_pk each); native per-lane k-order
      unsigned pk0[8], pk1[8];
#pragma unroll
      for (int m = 0; m < 8; ++m) {
        pk0[m] = cvt_pk_bf16(sa[0][2 * m], sa[0][2 * m + 1]);
        pk1[m] = cvt_pk_bf16(sa[1][2 * m], sa[1][2 * m + 1]);
      }
      // V^T fragments: read path unchanged; pi-storage makes content match
      // the A-frag's native k-order (k-permutation invariance of PV)
      bf16x8 vf[2][4];
#pragma unroll
      for (int dt = 0; dt < 2; ++dt)
#pragma unroll
        for (int ks = 0; ks < 4; ++ks) {
          int d = 32 * dt + l31;
          int ch = ((2 * ks + hi) ^ (d & 7) ^ ((d >> 3) & 7)) & 7;
          vf[dt][ks] = *(const bf16x8*)&Vt[d * 64 + (ch << 3)];
        }
      // PV A-frags: direct dword copy, NO cross-lane exchange
#pragma unroll
      for (int ks = 0; ks < 4; ++ks) {
        int c0 = 4 * (ks & 1);
        u32x4 fa;
        fa.x = (ks < 2) ? pk0[c0] : pk1[c0];
        fa.y = (ks < 2) ? pk0[c0 + 1] : pk1[c0 + 1];
        fa.z = (ks < 2) ? pk0[c0 + 2] : pk1[c0 + 2];
        fa.w = (ks < 2) ? pk0[c0 + 3] : pk1[c0 + 3];
        bf16x8 paf = __builtin_bit_cast(bf16x8, fa);
        __builtin_amdgcn_s_setprio(1);
#pragma unroll
        for (int dt = 0; dt < 2; ++dt)
          o_acc[dt] = __builtin_amdgcn_mfma_f32_32x32x16_bf16(
              paf, vf[dt][ks], o_acc[dt], 0, 0, 0);
        __builtin_amdgcn_s_setprio(0);
      }
    }
    __syncthreads();  // [B] Ks/Vt reads done before next tile's writes
  }

  l_run += __shfl_xor(l_run, 32);  // complete the deferred cross-half sum

  // epilogue: normalize and store
#pragma unroll
  for (int r = 0; r < 16; ++r) {
    int crow = (r & 3) + 8 * (r >> 2) + 4 * hi;
    float li = __shfl(l_run, crow + 32 * hi);
    float inv = 1.f / li;
    int q = q0w + crow;
#pragma unroll
    for (int dt = 0; dt < 2; ++dt) {
      float y = o_acc[dt][r] * inv;
      Yg[(size_t)(b * 2048 + q) * 1024 + h * 64 + dt * 32 + l31] = f2bf(y);
    }
  }
}

// ---------------- launch ----------------

extern "C" void kernel_launch(void* const* d_in, const int* in_sizes, int n_in,
                              void* d_out, int out_size, void* d_ws, size_t ws_size,
                              hipStream_t stream) {
  const float* x = (const float*)d_in[0];
  const float* w_qkv = (const float*)d_in[1];
  const float* w_proj = (const float*)d_in[2];
  float* out = (float*)d_out;
  u16* ws = (u16*)d_ws;

  u16* xb = ws;                  // 8388608 elems (B*T*C)
  u16* wq = xb + 8388608;        // 3145728 (3C x C, transposed)
  u16* wp = wq + 3145728;        // 1048576 (C x C, transposed)
  u16* Qb = wp + 1048576;        // 8388608 each, [B,H,T,D]
  u16* Kb = Qb + 8388608;
  u16* Vb = Kb + 8388608;
  u16* Yb = xb;                  // alias: x_bf16 dead after QKV GEMM

  cast_f32_bf16<<<8192, 256, 0, stream>>>(x, xb, 2097152);
  transpose_cast<<<dim3(96, 32), dim3(32, 8), 0, stream>>>(w_qkv, wq, 1024, 3072);
  transpose_cast<<<dim3(32, 32), dim3(32, 8), 0, stream>>>(w_proj, wp, 1024, 1024);
  gemm_bt<0><<<dim3(24, 64), 256, 0, stream>>>(xb, wq, 1024, Qb, Kb, Vb, nullptr, 3072);
  attn_fwd<<<2048, 128, 0, stream>>>(Qb, Kb, Vb, Yb);
  gemm_bt<1><<<dim3(8, 64), 256, 0, stream>>>(Yb, wp, 1024, nullptr, nullptr, nullptr, out, 1024);
}